// Round 6
// baseline (126.921 us; speedup 1.0000x reference)
//
#include <hip/hip_runtime.h>

#define E_EDGES 131072
#define N_NODES 4096
#define HOUT    64
#define NE_TOT  (4 * E_EDGES)
#define CAP     256            // per-row slot capacity (mean deg 128, ~11 sigma)

// ---------------------------------------------------------------- bf16 utils
__device__ __forceinline__ unsigned short f2bf(float x) {
    unsigned u = __float_as_uint(x);
    return (unsigned short)((u + 0x7FFFu + ((u >> 16) & 1u)) >> 16);   // RNE
}
__device__ __forceinline__ float bf2f(unsigned b) {
    return __uint_as_float(b << 16);
}

// ---------------------------------------------------------------- helpers
__device__ __forceinline__ void softmax4(const float* __restrict__ cw,
                                         int layer, int c, float f[4]) {
#pragma unroll
    for (int t = 0; t < 4; ++t) f[t] = cw[(layer * 2 + c) * 4 + t];
    float m = fmaxf(fmaxf(f[0], f[1]), fmaxf(f[2], f[3]));
    float s = 0.f;
#pragma unroll
    for (int t = 0; t < 4; ++t) { f[t] = expf(f[t] - m); s += f[t]; }
    float inv = 1.0f / s;
#pragma unroll
    for (int t = 0; t < 4; ++t) f[t] *= inv;
}

__device__ __forceinline__ float selw(const float f[4], int t) {
    float a = (t & 1) ? f[1] : f[0];
    float b = (t & 1) ? f[3] : f[2];
    return (t & 2) ? b : a;
}

__device__ __forceinline__ void fma8(float acc[8], float w, uint4 v) {
    acc[0] += w * bf2f(v.x & 0xFFFFu); acc[1] += w * bf2f(v.x >> 16);
    acc[2] += w * bf2f(v.y & 0xFFFFu); acc[3] += w * bf2f(v.y >> 16);
    acc[4] += w * bf2f(v.z & 0xFFFFu); acc[5] += w * bf2f(v.z >> 16);
    acc[6] += w * bf2f(v.w & 0xFFFFu); acc[7] += w * bf2f(v.w >> 16);
}

__device__ __forceinline__ uint4 pack8(const float acc[8]) {
    uint4 r;
    r.x = (unsigned)f2bf(acc[0]) | ((unsigned)f2bf(acc[1]) << 16);
    r.y = (unsigned)f2bf(acc[2]) | ((unsigned)f2bf(acc[3]) << 16);
    r.z = (unsigned)f2bf(acc[4]) | ((unsigned)f2bf(acc[5]) << 16);
    r.w = (unsigned)f2bf(acc[6]) | ((unsigned)f2bf(acc[7]) << 16);
    return r;
}

// wave-level SpMM over one row's slot: 8 edges/step (one per 8-lane group),
// each lane gathers a uint4 = 8 bf16 (group covers the 128B row = 1 line);
// 2x unrolled = 16 edges in flight; butterfly reduce across groups at the end.
// Result: every lane holds the 8 h-values for h = (lane&7)*8 + j.
__device__ __forceinline__ void spmm_row16(const uint2* __restrict__ erow, int len,
                                           const unsigned* __restrict__ Hc16,
                                           const float f[4], int lane, float acc[8]) {
    int g  = lane >> 3;       // edge slot within step (0..7)
    int hq = lane & 7;        // uint4 slot within the row
#pragma unroll
    for (int j = 0; j < 8; ++j) acc[j] = 0.f;
    int e = 0;
    for (; e + 16 <= len; e += 16) {
        uint2 r0 = erow[e + g];
        uint2 r1 = erow[e + 8 + g];
        float w0 = __uint_as_float(r0.y) * selw(f, (int)(r0.x >> 16));
        float w1 = __uint_as_float(r1.y) * selw(f, (int)(r1.x >> 16));
        uint4 v0 = ((const uint4*)(Hc16 + (r0.x & 0xFFFFu) * (HOUT / 2)))[hq];
        uint4 v1 = ((const uint4*)(Hc16 + (r1.x & 0xFFFFu) * (HOUT / 2)))[hq];
        fma8(acc, w0, v0);
        fma8(acc, w1, v1);
    }
    for (; e + 8 <= len; e += 8) {
        uint2 r0 = erow[e + g];
        float w0 = __uint_as_float(r0.y) * selw(f, (int)(r0.x >> 16));
        uint4 v0 = ((const uint4*)(Hc16 + (r0.x & 0xFFFFu) * (HOUT / 2)))[hq];
        fma8(acc, w0, v0);
    }
    if (g < len - e) {
        uint2 r0 = erow[e + g];
        float w0 = __uint_as_float(r0.y) * selw(f, (int)(r0.x >> 16));
        uint4 v0 = ((const uint4*)(Hc16 + (r0.x & 0xFFFFu) * (HOUT / 2)))[hq];
        fma8(acc, w0, v0);
    }
#pragma unroll
    for (int j = 0; j < 8; ++j) {
        acc[j] += __shfl_xor(acc[j], 8);
        acc[j] += __shfl_xor(acc[j], 16);
        acc[j] += __shfl_xor(acc[j], 32);
    }
}

// ---------------------------------------------- zero the slot cursors
__global__ void __launch_bounds__(256)
zero_kernel(int* __restrict__ cursor) {
    cursor[blockIdx.x * 256 + threadIdx.x] = 0;
}

// ------------- fused: blocks [0,2048) scatter 1 edge/thread;
//               blocks [2048,4096) compute H0 = X @ Ws1 (one (c,n,h)/thread)
__global__ void __launch_bounds__(256)
scatter_zinit_kernel(const int* __restrict__ ei, const float* __restrict__ ew,
                     int* __restrict__ cursor, uint2* __restrict__ edges,
                     const float* __restrict__ X, const float* __restrict__ Ws,
                     float* __restrict__ H0, unsigned* __restrict__ H016) {
    int b = blockIdx.x;
    if (b < NE_TOT / 256) {
        int i = b * 256 + threadIdx.x;
        int t = i >> 17;
        int e = i & (E_EDGES - 1);
        int   src = ei[(t * 2 + 0) * E_EDGES + e];
        int   dst = ei[(t * 2 + 1) * E_EDGES + e];
        float w   = ew[t * E_EDGES + e];
        int pos = atomicAdd(&cursor[src], 1);
        if (pos < CAP)
            edges[src * CAP + pos] =
                make_uint2((unsigned)dst | ((unsigned)t << 16), __float_as_uint(w));
    } else {
        int idx = (b - NE_TOT / 256) * 256 + threadIdx.x;   // c*N*64 + n*64 + h
        int h = idx & 63;
        int n = (idx >> 6) & (N_NODES - 1);
        int c = idx >> 18;
        const float4* xv = (const float4*)(X + n * 128);
        const float*  w  = Ws + c * 128 * HOUT + h;
        float acc = 0.f;
#pragma unroll 8
        for (int k4 = 0; k4 < 32; ++k4) {
            float4 xx = xv[k4];
            acc += xx.x * w[(k4 * 4 + 0) * HOUT];
            acc += xx.y * w[(k4 * 4 + 1) * HOUT];
            acc += xx.z * w[(k4 * 4 + 2) * HOUT];
            acc += xx.w * w[(k4 * 4 + 3) * HOUT];
        }
        H0[idx] = acc;
        ((unsigned short*)H016)[idx] = f2bf(acc);
    }
}

// ---------------------------------------------- layer-0 SpMM (bf16 in/out)
__global__ void __launch_bounds__(256)
spmm_kernel(const int* __restrict__ cnt, const uint2* __restrict__ edges,
            const unsigned* __restrict__ Hin16, unsigned* __restrict__ Hout16,
            const float* __restrict__ cw) {
    int task = (blockIdx.x * 256 + threadIdx.x) >> 6;   // 8192 = row*2 + c
    int lane = threadIdx.x & 63;
    int row  = task >> 1, c = task & 1;
    float f[4]; softmax4(cw, 0, c, f);
    int len = min(cnt[row], CAP);
    float acc[8];
    spmm_row16(edges + row * CAP, len, Hin16 + c * N_NODES * (HOUT / 2), f, lane, acc);
    if ((lane >> 3) == 0)    // 8 lanes write 8 uint4 = full 128B row
        ((uint4*)(Hout16 + (c * N_NODES + row) * (HOUT / 2)))[lane & 7] = pack8(acc);
}

// ------- layer-1 SpMM + beta-combine + linear (+ next-FastGTN init)
template <bool FINAL>
__global__ void __launch_bounds__(128)
tail_kernel(const int* __restrict__ cnt, const uint2* __restrict__ edges,
            const unsigned* __restrict__ Hin16,   // layer-1 conv input (bf16)
            const float* __restrict__ H0,         // X_ detached init (f32)
            const float* __restrict__ cw,
            const float* __restrict__ lw, const float* __restrict__ lb,
            const float* __restrict__ Wsn,
            float* __restrict__ outp, unsigned* __restrict__ out16) {
    __shared__ float hcomb[2 * HOUT];
    __shared__ float mids[HOUT];
    int tid  = threadIdx.x;       // 128 = 2 waves, wave == channel
    int c    = tid >> 6;
    int lane = tid & 63;
    int row  = blockIdx.x;

    float f[4]; softmax4(cw, 1, c, f);
    int len = min(cnt[row], CAP);
    float acc[8];
    spmm_row16(edges + row * CAP, len, Hin16 + c * N_NODES * (HOUT / 2), f, lane, acc);
    // H_ = relu(0.1*X_ + 0.9*H2): lanes g==0 hold h = hq*8+j
    if ((lane >> 3) == 0) {
        int hq = lane & 7;
#pragma unroll
        for (int j = 0; j < 8; ++j) {
            int h = hq * 8 + j;
            float h0v = H0[(c * N_NODES + row) * HOUT + h];
            hcomb[c * HOUT + h] = fmaxf(0.1f * h0v + 0.9f * acc[j], 0.f);
        }
    }
    __syncthreads();

    if (FINAL) {
        if (tid < 64) {
            float a = lb[tid];
#pragma unroll 8
            for (int j = 0; j < 2 * HOUT; ++j) a += hcomb[j] * lw[j * HOUT + tid];
            outp[row * HOUT + tid] = fmaxf(a, 0.f);
        }
    } else {
        if (tid < 64) {
            float a = lb[tid];
#pragma unroll 8
            for (int j = 0; j < 2 * HOUT; ++j) a += hcomb[j] * lw[j * HOUT + tid];
            mids[tid] = fmaxf(a, 0.f);
        }
        __syncthreads();
        // next FastGTN init: H0'[c,row,h] = sum_k mid[k] * Ws_next[c,k,h]
        float a = 0.f;
        const float* w = Wsn + c * HOUT * HOUT + lane;
#pragma unroll 8
        for (int k = 0; k < HOUT; ++k) a += mids[k] * w[k * HOUT];
        int o = (c * N_NODES + row) * HOUT + lane;
        outp[o] = a;
        ((unsigned short*)out16)[o] = f2bf(a);
    }
}

extern "C" void kernel_launch(void* const* d_in, const int* in_sizes, int n_in,
                              void* d_out, int out_size, void* d_ws, size_t ws_size,
                              hipStream_t stream) {
    const int*   ei  = (const int*)d_in[0];
    const float* ew  = (const float*)d_in[1];
    const float* X   = (const float*)d_in[2];
    const float* Ws1 = (const float*)d_in[3];
    const float* cw1 = (const float*)d_in[4];
    const float* lw1 = (const float*)d_in[5];
    const float* lb1 = (const float*)d_in[6];
    const float* Ws2 = (const float*)d_in[7];
    const float* cw2 = (const float*)d_in[8];
    const float* lw2 = (const float*)d_in[9];
    const float* lb2 = (const float*)d_in[10];
    float* outp = (float*)d_out;

    char* ws = (char*)d_ws;
    size_t off = 0;
    auto alloc = [&](size_t bytes) -> void* {
        void* p = ws + off;
        off += (bytes + 255) & ~size_t(255);
        return p;
    };
    int*      cursor = (int*)alloc(N_NODES * 4);
    uint2*    edges  = (uint2*)alloc((size_t)N_NODES * CAP * 8);
    float*    H0a    = (float*)alloc((size_t)2 * N_NODES * HOUT * 4);
    unsigned* H0a16  = (unsigned*)alloc((size_t)2 * N_NODES * HOUT * 2);
    unsigned* Ha16   = (unsigned*)alloc((size_t)2 * N_NODES * HOUT * 2);
    float*    H0b    = (float*)alloc((size_t)2 * N_NODES * HOUT * 4);
    unsigned* H0b16  = (unsigned*)alloc((size_t)2 * N_NODES * HOUT * 2);

    // FastGTN #1
    zero_kernel<<<N_NODES / 256, 256, 0, stream>>>(cursor);
    scatter_zinit_kernel<<<NE_TOT / 256 + 2048, 256, 0, stream>>>(
        ei, ew, cursor, edges, X, Ws1, H0a, H0a16);
    spmm_kernel<<<2048, 256, 0, stream>>>(cursor, edges, H0a16, Ha16, cw1);
    tail_kernel<false><<<N_NODES, 128, 0, stream>>>(
        cursor, edges, Ha16, H0a, cw1, lw1, lb1, Ws2, H0b, H0b16);

    // FastGTN #2
    spmm_kernel<<<2048, 256, 0, stream>>>(cursor, edges, H0b16, Ha16, cw2);
    tail_kernel<true><<<N_NODES, 128, 0, stream>>>(
        cursor, edges, Ha16, H0b, cw2, lw2, lb2, nullptr, outp, nullptr);
}

// Round 7
// 116.122 us; speedup vs baseline: 1.0930x; 1.0930x over previous
//
#include <hip/hip_runtime.h>

#define E_EDGES 131072
#define N_NODES 4096
#define HOUT    64
#define NE_TOT  (4 * E_EDGES)
#define CAP     256        // per-row slot capacity (mean deg 128, ~11 sigma)
#define CSTRIDE 16         // one cursor per 64B line

// ---------------------------------------------------------------- bf16 utils
__device__ __forceinline__ unsigned short f2bf(float x) {
    unsigned u = __float_as_uint(x);
    return (unsigned short)((u + 0x7FFFu + ((u >> 16) & 1u)) >> 16);   // RNE
}
__device__ __forceinline__ float bf2f(unsigned b) {
    return __uint_as_float(b << 16);
}

// ---------------------------------------------------------------- helpers
__device__ __forceinline__ void softmax4(const float* __restrict__ cw,
                                         int layer, int c, float f[4]) {
#pragma unroll
    for (int t = 0; t < 4; ++t) f[t] = cw[(layer * 2 + c) * 4 + t];
    float m = fmaxf(fmaxf(f[0], f[1]), fmaxf(f[2], f[3]));
    float s = 0.f;
#pragma unroll
    for (int t = 0; t < 4; ++t) { f[t] = expf(f[t] - m); s += f[t]; }
    float inv = 1.0f / s;
#pragma unroll
    for (int t = 0; t < 4; ++t) f[t] *= inv;
}

__device__ __forceinline__ float selw(const float f[4], int t) {
    float a = (t & 1) ? f[1] : f[0];
    float b = (t & 1) ? f[3] : f[2];
    return (t & 2) ? b : a;
}

__device__ __forceinline__ void fma8(float acc[8], float w, uint4 v) {
    acc[0] += w * bf2f(v.x & 0xFFFFu); acc[1] += w * bf2f(v.x >> 16);
    acc[2] += w * bf2f(v.y & 0xFFFFu); acc[3] += w * bf2f(v.y >> 16);
    acc[4] += w * bf2f(v.z & 0xFFFFu); acc[5] += w * bf2f(v.z >> 16);
    acc[6] += w * bf2f(v.w & 0xFFFFu); acc[7] += w * bf2f(v.w >> 16);
}

__device__ __forceinline__ uint4 pack8(const float acc[8]) {
    uint4 r;
    r.x = (unsigned)f2bf(acc[0]) | ((unsigned)f2bf(acc[1]) << 16);
    r.y = (unsigned)f2bf(acc[2]) | ((unsigned)f2bf(acc[3]) << 16);
    r.z = (unsigned)f2bf(acc[4]) | ((unsigned)f2bf(acc[5]) << 16);
    r.w = (unsigned)f2bf(acc[6]) | ((unsigned)f2bf(acc[7]) << 16);
    return r;
}

// Dual-channel wave-level SpMM over one row: 8 edges/step (one per 8-lane
// group), each lane gathers uint4 = 8 bf16 from BOTH channels' H rows
// (2 independent loads per edge -> 2x ILP); butterfly-reduce at the end.
// After reduce every lane holds, for hq = lane&7, h = hq*8+j: a0[j], a1[j].
__device__ __forceinline__ void spmm_row2c(const uint2* __restrict__ erow, int len,
                                           const unsigned* __restrict__ Hc0,
                                           const unsigned* __restrict__ Hc1,
                                           const float f0[4], const float f1[4],
                                           int lane, float a0[8], float a1[8]) {
    int g  = lane >> 3;       // edge slot within step (0..7)
    int hq = lane & 7;        // uint4 slot within the 128B row
#pragma unroll
    for (int j = 0; j < 8; ++j) { a0[j] = 0.f; a1[j] = 0.f; }
    int e = 0;
    for (; e + 16 <= len; e += 16) {
        uint2 r0 = erow[e + g];
        uint2 r1 = erow[e + 8 + g];
        float w0 = __uint_as_float(r0.y);
        float w1 = __uint_as_float(r1.y);
        int   d0 = r0.x & 0xFFFFu, t0 = (int)(r0.x >> 16);
        int   d1 = r1.x & 0xFFFFu, t1 = (int)(r1.x >> 16);
        uint4 v00 = ((const uint4*)(Hc0 + d0 * (HOUT / 2)))[hq];
        uint4 v01 = ((const uint4*)(Hc1 + d0 * (HOUT / 2)))[hq];
        uint4 v10 = ((const uint4*)(Hc0 + d1 * (HOUT / 2)))[hq];
        uint4 v11 = ((const uint4*)(Hc1 + d1 * (HOUT / 2)))[hq];
        fma8(a0, w0 * selw(f0, t0), v00);
        fma8(a1, w0 * selw(f1, t0), v01);
        fma8(a0, w1 * selw(f0, t1), v10);
        fma8(a1, w1 * selw(f1, t1), v11);
    }
    for (; e + 8 <= len; e += 8) {
        uint2 r0 = erow[e + g];
        float w0 = __uint_as_float(r0.y);
        int   d0 = r0.x & 0xFFFFu, t0 = (int)(r0.x >> 16);
        uint4 v00 = ((const uint4*)(Hc0 + d0 * (HOUT / 2)))[hq];
        uint4 v01 = ((const uint4*)(Hc1 + d0 * (HOUT / 2)))[hq];
        fma8(a0, w0 * selw(f0, t0), v00);
        fma8(a1, w0 * selw(f1, t0), v01);
    }
    if (g < len - e) {
        uint2 r0 = erow[e + g];
        float w0 = __uint_as_float(r0.y);
        int   d0 = r0.x & 0xFFFFu, t0 = (int)(r0.x >> 16);
        uint4 v00 = ((const uint4*)(Hc0 + d0 * (HOUT / 2)))[hq];
        uint4 v01 = ((const uint4*)(Hc1 + d0 * (HOUT / 2)))[hq];
        fma8(a0, w0 * selw(f0, t0), v00);
        fma8(a1, w0 * selw(f1, t0), v01);
    }
#pragma unroll
    for (int j = 0; j < 8; ++j) {
        a0[j] += __shfl_xor(a0[j], 8);
        a0[j] += __shfl_xor(a0[j], 16);
        a0[j] += __shfl_xor(a0[j], 32);
        a1[j] += __shfl_xor(a1[j], 8);
        a1[j] += __shfl_xor(a1[j], 16);
        a1[j] += __shfl_xor(a1[j], 32);
    }
}

// ---------------------------------------------- zero the (padded) cursors
__global__ void __launch_bounds__(256)
zero_kernel(int* __restrict__ cursor) {
    cursor[blockIdx.x * 256 + threadIdx.x] = 0;
}

// ---------------------------------------------- H0 = X @ Ws1 (f32 + bf16 copy)
__global__ void __launch_bounds__(256)
zinit_kernel(const float* __restrict__ X, const float* __restrict__ Ws,
             float* __restrict__ H0, unsigned* __restrict__ H016) {
    int idx = blockIdx.x * 256 + threadIdx.x;   // c*N*64 + n*64 + h
    int h = idx & 63;
    int n = (idx >> 6) & (N_NODES - 1);
    int c = idx >> 18;
    const float4* xv = (const float4*)(X + n * 128);
    const float*  w  = Ws + c * 128 * HOUT + h;
    float acc = 0.f;
#pragma unroll 8
    for (int k4 = 0; k4 < 32; ++k4) {
        float4 xx = xv[k4];
        acc += xx.x * w[(k4 * 4 + 0) * HOUT];
        acc += xx.y * w[(k4 * 4 + 1) * HOUT];
        acc += xx.z * w[(k4 * 4 + 2) * HOUT];
        acc += xx.w * w[(k4 * 4 + 3) * HOUT];
    }
    H0[idx] = acc;
    ((unsigned short*)H016)[idx] = f2bf(acc);
}

// ---------------------------------------------- slot scatter, 1 edge/thread
__global__ void __launch_bounds__(256)
scatter_kernel(const int* __restrict__ ei, const float* __restrict__ ew,
               int* __restrict__ cursor, uint2* __restrict__ edges) {
    int i = blockIdx.x * 256 + threadIdx.x;
    int t = i >> 17;
    int e = i & (E_EDGES - 1);
    int   src = ei[(t * 2 + 0) * E_EDGES + e];
    int   dst = ei[(t * 2 + 1) * E_EDGES + e];
    float w   = ew[t * E_EDGES + e];
    int pos = atomicAdd(&cursor[src * CSTRIDE], 1);
    if (pos < CAP)
        edges[src * CAP + pos] =
            make_uint2((unsigned)dst | ((unsigned)t << 16), __float_as_uint(w));
}

// ---------------------------------------------- layer-0 SpMM, both channels
__global__ void __launch_bounds__(256)
spmm_kernel(const int* __restrict__ cnt, const uint2* __restrict__ edges,
            const unsigned* __restrict__ Hin16, unsigned* __restrict__ Hout16,
            const float* __restrict__ cw) {
    int row  = (blockIdx.x * 256 + threadIdx.x) >> 6;   // 4096 waves = rows
    int lane = threadIdx.x & 63;
    float f0[4], f1[4];
    softmax4(cw, 0, 0, f0);
    softmax4(cw, 0, 1, f1);
    int len = min(cnt[row * CSTRIDE], CAP);
    float a0[8], a1[8];
    spmm_row2c(edges + row * CAP, len,
               Hin16, Hin16 + N_NODES * (HOUT / 2), f0, f1, lane, a0, a1);
    if ((lane >> 3) == 0) {
        int hq = lane & 7;
        ((uint4*)(Hout16 + row * (HOUT / 2)))[hq] = pack8(a0);
        ((uint4*)(Hout16 + (N_NODES + row) * (HOUT / 2)))[hq] = pack8(a1);
    }
}

// ------- layer-1 SpMM + beta-combine + linear (+ next-FastGTN init)
// 256 threads = 4 waves, one wave per row (both channels in-wave)
template <bool FINAL>
__global__ void __launch_bounds__(256)
tail_kernel(const int* __restrict__ cnt, const uint2* __restrict__ edges,
            const unsigned* __restrict__ Hin16,   // layer-1 conv input (bf16)
            const float* __restrict__ H0,         // X_ detached init (f32)
            const float* __restrict__ cw,
            const float* __restrict__ lw, const float* __restrict__ lb,
            const float* __restrict__ Wsn,
            float* __restrict__ outp, unsigned* __restrict__ out16) {
    __shared__ float hcomb[4][2 * HOUT];
    __shared__ float mids[4][HOUT];
    int tid  = threadIdx.x;
    int r    = tid >> 6;          // row within block
    int lane = tid & 63;
    int row  = blockIdx.x * 4 + r;

    float f0[4], f1[4];
    softmax4(cw, 1, 0, f0);
    softmax4(cw, 1, 1, f1);
    int len = min(cnt[row * CSTRIDE], CAP);
    float a0[8], a1[8];
    spmm_row2c(edges + row * CAP, len,
               Hin16, Hin16 + N_NODES * (HOUT / 2), f0, f1, lane, a0, a1);

    // H_ = relu(0.1*X_ + 0.9*H2) for both channels, j = c*64 + h
    if ((lane >> 3) == 0) {
        int hq = lane & 7;
#pragma unroll
        for (int j = 0; j < 8; ++j) {
            int h = hq * 8 + j;
            float h00 = H0[row * HOUT + h];
            float h01 = H0[(N_NODES + row) * HOUT + h];
            hcomb[r][h]        = fmaxf(0.1f * h00 + 0.9f * a0[j], 0.f);
            hcomb[r][HOUT + h] = fmaxf(0.1f * h01 + 0.9f * a1[j], 0.f);
        }
    }
    __syncthreads();

    float a = lb[lane];
#pragma unroll 8
    for (int j = 0; j < 2 * HOUT; ++j) a += hcomb[r][j] * lw[j * HOUT + lane];

    if (FINAL) {
        outp[row * HOUT + lane] = fmaxf(a, 0.f);
    } else {
        mids[r][lane] = fmaxf(a, 0.f);
        __syncthreads();
        // next FastGTN init: H0'[c,row,h] = sum_k mid[k] * Ws_next[c,k,h]
#pragma unroll
        for (int c = 0; c < 2; ++c) {
            float acc = 0.f;
            const float* w = Wsn + c * HOUT * HOUT + lane;
#pragma unroll 8
            for (int k = 0; k < HOUT; ++k) acc += mids[r][k] * w[k * HOUT];
            int o = (c * N_NODES + row) * HOUT + lane;
            outp[o] = acc;
            ((unsigned short*)out16)[o] = f2bf(acc);
        }
    }
}

extern "C" void kernel_launch(void* const* d_in, const int* in_sizes, int n_in,
                              void* d_out, int out_size, void* d_ws, size_t ws_size,
                              hipStream_t stream) {
    const int*   ei  = (const int*)d_in[0];
    const float* ew  = (const float*)d_in[1];
    const float* X   = (const float*)d_in[2];
    const float* Ws1 = (const float*)d_in[3];
    const float* cw1 = (const float*)d_in[4];
    const float* lw1 = (const float*)d_in[5];
    const float* lb1 = (const float*)d_in[6];
    const float* Ws2 = (const float*)d_in[7];
    const float* cw2 = (const float*)d_in[8];
    const float* lw2 = (const float*)d_in[9];
    const float* lb2 = (const float*)d_in[10];
    float* outp = (float*)d_out;

    char* ws = (char*)d_ws;
    size_t off = 0;
    auto alloc = [&](size_t bytes) -> void* {
        void* p = ws + off;
        off += (bytes + 255) & ~size_t(255);
        return p;
    };
    int*      cursor = (int*)alloc((size_t)N_NODES * CSTRIDE * 4);
    uint2*    edges  = (uint2*)alloc((size_t)N_NODES * CAP * 8);
    float*    H0a    = (float*)alloc((size_t)2 * N_NODES * HOUT * 4);
    unsigned* H0a16  = (unsigned*)alloc((size_t)2 * N_NODES * HOUT * 2);
    unsigned* Ha16   = (unsigned*)alloc((size_t)2 * N_NODES * HOUT * 2);
    float*    H0b    = (float*)alloc((size_t)2 * N_NODES * HOUT * 4);
    unsigned* H0b16  = (unsigned*)alloc((size_t)2 * N_NODES * HOUT * 2);

    zero_kernel   <<<(N_NODES * CSTRIDE) / 256, 256, 0, stream>>>(cursor);
    zinit_kernel  <<<2048, 256, 0, stream>>>(X, Ws1, H0a, H0a16);
    scatter_kernel<<<NE_TOT / 256, 256, 0, stream>>>(ei, ew, cursor, edges);

    // FastGTN #1
    spmm_kernel<<<1024, 256, 0, stream>>>(cursor, edges, H0a16, Ha16, cw1);
    tail_kernel<false><<<1024, 256, 0, stream>>>(
        cursor, edges, Ha16, H0a, cw1, lw1, lb1, Ws2, H0b, H0b16);

    // FastGTN #2
    spmm_kernel<<<1024, 256, 0, stream>>>(cursor, edges, H0b16, Ha16, cw2);
    tail_kernel<true><<<1024, 256, 0, stream>>>(
        cursor, edges, Ha16, H0b, cw2, lw2, lb2, nullptr, outp, nullptr);
}